// Round 1
// baseline (319.215 us; speedup 1.0000x reference)
//
#include <hip/hip_runtime.h>
#include <hip/hip_bf16.h>
#include <math.h>

// Shapes (fixed): B=2048, D=1024, H=1024, Z=256, E=64
// out = concat(h1[B,H], c1[B,H], hhat1[B,Z], chat1[B,Z]) fp32

typedef __attribute__((ext_vector_type(8))) short bf16x8;   // MFMA A/B frag (8 bf16)
typedef __attribute__((ext_vector_type(4))) float f32x4;    // MFMA C/D frag

__device__ __forceinline__ unsigned short f2b(float f) {
  union { float f; unsigned u; } v; v.f = f;
  unsigned r = v.u + 0x7fffu + ((v.u >> 16) & 1u);   // RNE
  return (unsigned short)(r >> 16);
}
__device__ __forceinline__ float sigm(float x) { return 1.f / (1.f + __expf(-x)); }

#define GLL16(gsrc, ldst)                                                      \
  __builtin_amdgcn_global_load_lds(                                            \
      (const __attribute__((address_space(1))) void*)(gsrc),                   \
      (__attribute__((address_space(3))) void*)(ldst), 16, 0, 0)

// ---------------- pack kernels (fp32 -> bf16) ----------------

// hcat[b][c] : c<256 -> hhat0, c<1280 -> h0, else x.  grid(9,2048) x 256
__global__ void k_pack_hcat(const float* __restrict__ hhat0, const float* __restrict__ h0,
                            const float* __restrict__ x, unsigned short* __restrict__ out) {
  int b = blockIdx.y;
  int c = blockIdx.x * 256 + threadIdx.x;          // < 2304
  float v = (c < 256) ? hhat0[b * 256 + c]
          : (c < 1280) ? h0[b * 1024 + (c - 256)]
                       : x[b * 1024 + (c - 1280)];
  out[(long)b * 2304 + c] = f2b(v);
}

// catx[b][c] : c<1024 -> h0, else x.  grid(8,2048) x 256
__global__ void k_pack_catx(const float* __restrict__ h0, const float* __restrict__ x,
                            unsigned short* __restrict__ out) {
  int b = blockIdx.y;
  int c = blockIdx.x * 256 + threadIdx.x;          // < 2048
  float v = (c < 1024) ? h0[b * 1024 + c] : x[b * 1024 + (c - 1024)];
  out[(long)b * 2048 + c] = f2b(v);
}

// transpose-convert: out[c][r] = bf16(in[r][c]).  in: [R][C] fp32.  batched on z.
__global__ void k_transpose_bf16(const float* __restrict__ in, unsigned short* __restrict__ out,
                                 int R, int C, long inBatch, long outBatch) {
  __shared__ float tile[32][33];
  const float* src = in + (long)blockIdx.z * inBatch;
  unsigned short* dst = out + (long)blockIdx.z * outBatch;
  int r0 = blockIdx.y * 32, c0 = blockIdx.x * 32;
  int tx = threadIdx.x & 31, ty = threadIdx.x >> 5;     // 32 x 8
  #pragma unroll
  for (int i = 0; i < 32; i += 8) {
    int r = r0 + ty + i, c = c0 + tx;
    tile[ty + i][tx] = (r < R && c < C) ? src[(long)r * C + c] : 0.f;
  }
  __syncthreads();
  #pragma unroll
  for (int i = 0; i < 32; i += 8) {
    int c = c0 + ty + i, r = r0 + tx;
    if (c < C && r < R) dst[(long)c * R + r] = f2b(tile[tx][ty + i]);
  }
}

// zbias_pack[768] = [zbias_h | zbias_x | 0]
__global__ void k_pack_zbias(const float* __restrict__ zh, const float* __restrict__ zx,
                             float* __restrict__ out) {
  int i = blockIdx.x * 256 + threadIdx.x;  // < 768
  out[i] = (i < 256) ? zh[i] : (i < 512) ? zx[i - 256] : 0.f;
}

// ---------------- bf16 MFMA GEMM ----------------
// A: [M][K] bf16 row-major.  Bt: [N][K] bf16 (i.e. B transposed).  C = A @ B  [M][N]
// 256 threads = 4 waves in 2x2; wave tile (BM/2)x(BN/2); 16x16x32 MFMA frags.
template <int BM, int BN>
__global__ __launch_bounds__(256, 2)
void k_gemm_bf16(const unsigned short* __restrict__ A, const unsigned short* __restrict__ Bt,
                 float* __restrict__ C, unsigned short* __restrict__ Cb,
                 const float* __restrict__ bias, int M, int N, int K) {
  constexpr int BK = 32;
  __shared__ __align__(16) unsigned short sA[BM * BK];
  __shared__ __align__(16) unsigned short sB[BN * BK];
  const int m0 = blockIdx.y * BM;
  const int n0 = blockIdx.x * BN;
  const int tid = threadIdx.x;
  const int wave = tid >> 6, lane = tid & 63;
  const int quad = lane >> 4, lrow = lane & 15;
  constexpr int WM = BM / 2, WN = BN / 2;
  constexpr int TM = WM / 16, TN = WN / 16;
  const int wm = (wave >> 1) * WM, wn = (wave & 1) * WN;
  constexpr int AIT = BM / 64;   // global_load_lds rounds for A (4KB per round)
  constexpr int BIT = BN / 64;

  const f32x4 vz = {0.f, 0.f, 0.f, 0.f};
  f32x4 acc[TM][TN];
  #pragma unroll
  for (int i = 0; i < TM; ++i)
    #pragma unroll
    for (int j = 0; j < TN; ++j) acc[i][j] = vz;

  for (int k0 = 0; k0 < K; k0 += BK) {
    #pragma unroll
    for (int c = 0; c < AIT; ++c) {
      int linear = c * 4096 + wave * 1024 + lane * 16;   // byte offset in 64B-row tile
      int row = linear >> 6, colb = linear & 63;
      const char* g = (const char*)A + ((long)(m0 + row) * K + k0) * 2 + colb;
      GLL16(g, (char*)sA + c * 4096 + wave * 1024);
    }
    #pragma unroll
    for (int c = 0; c < BIT; ++c) {
      int linear = c * 4096 + wave * 1024 + lane * 16;
      int row = linear >> 6, colb = linear & 63;
      const char* g = (const char*)Bt + ((long)(n0 + row) * K + k0) * 2 + colb;
      GLL16(g, (char*)sB + c * 4096 + wave * 1024);
    }
    __syncthreads();
    bf16x8 af[TM], bfr[TN];
    #pragma unroll
    for (int i = 0; i < TM; ++i)
      af[i] = *(const bf16x8*)&sA[(wm + i * 16 + lrow) * BK + quad * 8];
    #pragma unroll
    for (int j = 0; j < TN; ++j)
      bfr[j] = *(const bf16x8*)&sB[(wn + j * 16 + lrow) * BK + quad * 8];
    #pragma unroll
    for (int i = 0; i < TM; ++i)
      #pragma unroll
      for (int j = 0; j < TN; ++j)
        acc[i][j] = __builtin_amdgcn_mfma_f32_16x16x32_bf16(af[i], bfr[j], acc[i][j], 0, 0, 0);
    __syncthreads();
  }
  // epilogue: D row=quad*4+r, col=lane&15
  #pragma unroll
  for (int i = 0; i < TM; ++i) {
    #pragma unroll
    for (int j = 0; j < TN; ++j) {
      #pragma unroll
      for (int r = 0; r < 4; ++r) {
        int row = m0 + wm + i * 16 + quad * 4 + r;
        int col = n0 + wn + j * 16 + lrow;
        float v = acc[i][j][r];
        if (bias) v += bias[col];
        if (C) C[(long)row * N + col] = v;
        if (Cb) Cb[(long)row * N + col] = f2b(v);
      }
    }
  }
}

// ---------------- fused block-diag d-einsum + modulation ----------------
// z: [2048][768] bf16 (cols t*256+g*64+e). dwT: [t][g][h:1024][e:64] bf16.
// gmod[b][n] = graw[b][n]*d_h*d_x + d_b + bias[n], n in [0,4096), gate g = n>>10.
__global__ __launch_bounds__(256)
void k_dmod(const unsigned short* __restrict__ z, const unsigned short* __restrict__ dwT,
            const float* __restrict__ graw, const float* __restrict__ bias,
            float* __restrict__ gmod) {
  __shared__ __align__(16) unsigned short sZ[64 * 64];  // [b_local][e]
  __shared__ __align__(16) unsigned short sW[64 * 64];  // [h_local][e]
  const int m0 = blockIdx.y * 64;
  const int n0 = blockIdx.x * 64;
  const int g = n0 >> 10;
  const int hcol = n0 & 1023;
  const int tid = threadIdx.x, wave = tid >> 6, lane = tid & 63;
  const int quad = lane >> 4, lrow = lane & 15;
  const int wm = (wave >> 1) * 32, wn = (wave & 1) * 32;

  const f32x4 vz4 = {0.f, 0.f, 0.f, 0.f};
  f32x4 acc[3][2][2];
  #pragma unroll
  for (int t = 0; t < 3; ++t)
    #pragma unroll
    for (int i = 0; i < 2; ++i)
      #pragma unroll
      for (int j = 0; j < 2; ++j) acc[t][i][j] = vz4;

  for (int t = 0; t < 3; ++t) {
    #pragma unroll
    for (int c = 0; c < 2; ++c) {
      int linear = c * 4096 + wave * 1024 + lane * 16;  // 128B rows
      int row = linear >> 7, colb = linear & 127;
      const char* gz = (const char*)z + ((long)(m0 + row) * 768 + t * 256 + g * 64) * 2 + colb;
      GLL16(gz, (char*)sZ + c * 4096 + wave * 1024);
      const char* gw = (const char*)dwT + ((long)((t * 4 + g) * 1024 + hcol) * 64) * 2 + linear;
      GLL16(gw, (char*)sW + c * 4096 + wave * 1024);
    }
    __syncthreads();
    #pragma unroll
    for (int kk = 0; kk < 2; ++kk) {   // K=64 -> 2 x 32
      bf16x8 za[2], wb[2];
      #pragma unroll
      for (int i = 0; i < 2; ++i)
        za[i] = *(const bf16x8*)&sZ[(wm + i * 16 + lrow) * 64 + kk * 32 + quad * 8];
      #pragma unroll
      for (int j = 0; j < 2; ++j)
        wb[j] = *(const bf16x8*)&sW[(wn + j * 16 + lrow) * 64 + kk * 32 + quad * 8];
      #pragma unroll
      for (int i = 0; i < 2; ++i)
        #pragma unroll
        for (int j = 0; j < 2; ++j)
          acc[t][i][j] = __builtin_amdgcn_mfma_f32_16x16x32_bf16(za[i], wb[j], acc[t][i][j], 0, 0, 0);
    }
    __syncthreads();
  }
  #pragma unroll
  for (int i = 0; i < 2; ++i) {
    #pragma unroll
    for (int j = 0; j < 2; ++j) {
      #pragma unroll
      for (int r = 0; r < 4; ++r) {
        int row = m0 + wm + i * 16 + quad * 4 + r;
        int col = n0 + wn + j * 16 + lrow;
        long idx = (long)row * 4096 + col;
        float v = graw[idx] * acc[0][i][j][r] * acc[1][i][j][r] + acc[2][i][j][r] + bias[col];
        gmod[idx] = v;
      }
    }
  }
}

// ---------------- elementwise LSTM cells ----------------

__global__ void k_hyper_act(const float* __restrict__ hg, const float* __restrict__ chat0,
                            float* __restrict__ chat1, float* __restrict__ hhat1,
                            unsigned short* __restrict__ hhat1b) {
  int idx = blockIdx.x * 256 + threadIdx.x;        // over 2048*256
  int b = idx >> 8, zc = idx & 255;
  const float* row = hg + (long)b * 1024;
  float ih = row[zc], gh = row[256 + zc], fh = row[512 + zc], oh = row[768 + zc];
  float c = sigm(fh) * chat0[idx] + sigm(ih) * tanhf(gh);
  float h = sigm(oh) * tanhf(c);
  chat1[idx] = c;
  hhat1[idx] = h;
  hhat1b[idx] = f2b(h);
}

__global__ void k_lstm_act(const float* __restrict__ gm, const float* __restrict__ c0,
                           float* __restrict__ h1, float* __restrict__ c1) {
  int idx = blockIdx.x * 256 + threadIdx.x;        // over 2048*1024
  int b = idx >> 10, hc = idx & 1023;
  const float* row = gm + (long)b * 4096;
  float ig = row[hc], gg = row[1024 + hc], fg = row[2048 + hc], og = row[3072 + hc];
  float c = sigm(fg) * c0[idx] + sigm(ig) * tanhf(gg);
  float h = sigm(og) * tanhf(c);
  c1[idx] = c;
  h1[idx] = h;
}

// ---------------- launch ----------------

extern "C" void kernel_launch(void* const* d_in, const int* in_sizes, int n_in,
                              void* d_out, int out_size, void* d_ws, size_t ws_size,
                              hipStream_t stream) {
  const float* x      = (const float*)d_in[0];
  const float* h0     = (const float*)d_in[1];
  const float* c0     = (const float*)d_in[2];
  const float* hhat0  = (const float*)d_in[3];
  const float* chat0  = (const float*)d_in[4];
  const float* hweight= (const float*)d_in[5];
  const float* hbias  = (const float*)d_in[6];
  const float* zw_h   = (const float*)d_in[7];
  const float* zw_x   = (const float*)d_in[8];
  const float* zw_b   = (const float*)d_in[9];
  const float* zb_h   = (const float*)d_in[10];
  const float* zb_x   = (const float*)d_in[11];
  const float* dw_h   = (const float*)d_in[12];
  const float* dw_x   = (const float*)d_in[13];
  const float* dw_b   = (const float*)d_in[14];
  const float* weight = (const float*)d_in[15];
  const float* bias   = (const float*)d_in[16];
  float* out = (float*)d_out;

  char* w = (char*)d_ws;
  auto take = [&](size_t bytes) { char* p = w; w += (bytes + 255) & ~(size_t)255; return p; };
  unsigned short* hcatb  = (unsigned short*)take(2048ull * 2304 * 2);
  unsigned short* hwT    = (unsigned short*)take(1024ull * 2304 * 2);
  unsigned short* catxb  = (unsigned short*)take(2048ull * 2048 * 2);
  unsigned short* wT     = (unsigned short*)take(4096ull * 2048 * 2);
  unsigned short* zwT    = (unsigned short*)take(768ull * 256 * 2);
  unsigned short* dwT    = (unsigned short*)take(12ull * 1024 * 64 * 2);
  float*          zbiasp = (float*)take(768 * 4);
  float*          hg     = (float*)take(2048ull * 1024 * 4);
  float*          graw   = (float*)take(2048ull * 4096 * 4);
  unsigned short* hhat1b = (unsigned short*)take(2048ull * 256 * 2);
  unsigned short* zb16   = (unsigned short*)take(2048ull * 768 * 2);

  // ---- pack / transpose (fp32 -> bf16) ----
  k_pack_hcat<<<dim3(9, 2048), 256, 0, stream>>>(hhat0, h0, x, hcatb);
  k_pack_catx<<<dim3(8, 2048), 256, 0, stream>>>(h0, x, catxb);
  k_transpose_bf16<<<dim3(32, 72, 1), 256, 0, stream>>>(hweight, hwT, 2304, 1024, 0, 0);
  k_transpose_bf16<<<dim3(128, 64, 1), 256, 0, stream>>>(weight, wT, 2048, 4096, 0, 0);
  k_transpose_bf16<<<dim3(8, 8, 1), 256, 0, stream>>>(zw_h, zwT, 256, 256, 0, 0);
  k_transpose_bf16<<<dim3(8, 8, 1), 256, 0, stream>>>(zw_x, zwT + 256 * 256, 256, 256, 0, 0);
  k_transpose_bf16<<<dim3(8, 8, 1), 256, 0, stream>>>(zw_b, zwT + 512 * 256, 256, 256, 0, 0);
  k_transpose_bf16<<<dim3(32, 2, 4), 256, 0, stream>>>(dw_h, dwT, 64, 1024, 64 * 1024, 64 * 1024);
  k_transpose_bf16<<<dim3(32, 2, 4), 256, 0, stream>>>(dw_x, dwT + 4 * 65536, 64, 1024, 64 * 1024, 64 * 1024);
  k_transpose_bf16<<<dim3(32, 2, 4), 256, 0, stream>>>(dw_b, dwT + 8 * 65536, 64, 1024, 64 * 1024, 64 * 1024);
  k_pack_zbias<<<3, 256, 0, stream>>>(zb_h, zb_x, zbiasp);

  // ---- main GEMM (independent of hyper chain): gates_raw = [h0,x] @ weight ----
  k_gemm_bf16<128, 128><<<dim3(32, 16), 256, 0, stream>>>(catxb, wT, graw, nullptr, nullptr,
                                                          2048, 4096, 2048);
  // ---- hyper GEMM: hg = hcat @ hweight + hbias ----
  k_gemm_bf16<64, 128><<<dim3(8, 32), 256, 0, stream>>>(hcatb, hwT, hg, nullptr, hbias,
                                                        2048, 1024, 2304);
  // ---- hyper cell -> chat1, hhat1 ----
  k_hyper_act<<<2048, 256, 0, stream>>>(hg, chat0,
                                        out + 2 * 2048 * 1024 + 2048 * 256,  // chat1
                                        out + 2 * 2048 * 1024,               // hhat1
                                        hhat1b);
  // ---- z = hhat1 @ [zw_h|zw_x|zw_b] + [zb_h|zb_x|0]  (bf16 out only) ----
  k_gemm_bf16<64, 128><<<dim3(6, 32), 256, 0, stream>>>(hhat1b, zwT, nullptr, zb16, zbiasp,
                                                        2048, 768, 256);
  // ---- fused d-einsum + modulation (in-place on graw) ----
  k_dmod<<<dim3(64, 32), 256, 0, stream>>>(zb16, dwT, graw, bias, graw);
  // ---- main cell -> h1, c1 ----
  k_lstm_act<<<8192, 256, 0, stream>>>(graw, c0, out, out + 2048 * 1024);
}

// Round 2
// 273.925 us; speedup vs baseline: 1.1653x; 1.1653x over previous
//
#include <hip/hip_runtime.h>
#include <hip/hip_bf16.h>
#include <math.h>

// Shapes (fixed): B=2048, D=1024, H=1024, Z=256, E=64
// out = concat(h1[B,H], c1[B,H], hhat1[B,Z], chat1[B,Z]) fp32
//
// Plan: one combined bf16 GEMM C[2048][5120] = hcat[2048][2304] @ [0|W ; hW]
//   cols 0..4095  = gates_raw ([h0,x]@weight via zero-padded K<256)
//   cols 4096..   = hg (hcat@hweight)
// then hyper cell -> z GEMM -> fused dmod+main cell.

typedef __attribute__((ext_vector_type(8))) short bf16x8;   // MFMA A/B frag
typedef __attribute__((ext_vector_type(4))) float f32x4;    // MFMA C/D frag

__device__ __forceinline__ unsigned short f2b(float f) {
  union { float f; unsigned u; } v; v.f = f;
  unsigned r = v.u + 0x7fffu + ((v.u >> 16) & 1u);   // RNE
  return (unsigned short)(r >> 16);
}
__device__ __forceinline__ float sigm(float x) { return 1.f / (1.f + __expf(-x)); }

#define GLL16(gsrc, ldst)                                                      \
  __builtin_amdgcn_global_load_lds(                                            \
      (const __attribute__((address_space(1))) void*)(gsrc),                   \
      (__attribute__((address_space(3))) void*)(ldst), 16, 0, 0)

// ---------------- pack hcat = [hhat0|h0|x] -> bf16 [2048][2304], float4 vectorized ----
__global__ void k_pack_hcat(const float* __restrict__ hhat0, const float* __restrict__ h0,
                            const float* __restrict__ x, unsigned short* __restrict__ out) {
  int i = blockIdx.x * 256 + threadIdx.x;          // over 2048*576 float4s
  int b = i / 576, c4 = i % 576;
  const float* src;
  if (c4 < 64)       src = hhat0 + (long)b * 256 + c4 * 4;
  else if (c4 < 320) src = h0 + (long)b * 1024 + (c4 - 64) * 4;
  else               src = x + (long)b * 1024 + (c4 - 320) * 4;
  float4 v = *(const float4*)src;
  ushort4 o = {f2b(v.x), f2b(v.y), f2b(v.z), f2b(v.w)};
  *(ushort4*)&out[(long)b * 2304 + c4 * 4] = o;
}

// ---------------- build combined Bt [5120][2304] bf16 ----------------
// n<4096: k<256 -> 0, else weight[k-256][n].  n>=4096: hweight[k][n-4096].
// Tile: 32 n x 64 k. grid (160, 36).
__global__ void k_build_bt(const float* __restrict__ weight, const float* __restrict__ hweight,
                           unsigned short* __restrict__ bt) {
  const int n0 = blockIdx.x * 32, k0 = blockIdx.y * 64;
  const int t = threadIdx.x;
  if (n0 < 4096 && k0 < 256) {          // zero region (block-uniform)
    ushort4 z4 = {0, 0, 0, 0};
    #pragma unroll
    for (int p = 0; p < 2; ++p) {
      int kc = t & 15, cl = (t >> 4) + 16 * p;
      *(ushort4*)&bt[(long)(n0 + cl) * 2304 + k0 + 4 * kc] = z4;
    }
    return;
  }
  __shared__ float tile[32][66];
  const float* src; int C, sc0, sr0;
  if (n0 >= 4096) { src = hweight; C = 1024; sc0 = n0 - 4096; sr0 = k0; }
  else            { src = weight;  C = 4096; sc0 = n0;        sr0 = k0 - 256; }
  #pragma unroll
  for (int p = 0; p < 8; ++p) {
    int c = t & 31, r = (t >> 5) + 8 * p;
    tile[c][r] = src[(long)(sr0 + r) * C + sc0 + c];
  }
  __syncthreads();
  #pragma unroll
  for (int p = 0; p < 2; ++p) {
    int kc = t & 15, cl = (t >> 4) + 16 * p;
    ushort4 o = {f2b(tile[cl][4 * kc]), f2b(tile[cl][4 * kc + 1]),
                 f2b(tile[cl][4 * kc + 2]), f2b(tile[cl][4 * kc + 3])};
    *(ushort4*)&bt[(long)(n0 + cl) * 2304 + k0 + 4 * kc] = o;
  }
}

// ---------------- all small transposes: zwT (3x 256x256) + dwT (12x 64x1024->1024x64) ----
// grid (32, 15): y<3 -> zw slice y; y>=3 -> dw slice (t=(y-3)/4, g=(y-3)%4).
__global__ void k_small_t(const float* __restrict__ zw_h, const float* __restrict__ zw_x,
                          const float* __restrict__ zw_b, const float* __restrict__ dw_h,
                          const float* __restrict__ dw_x, const float* __restrict__ dw_b,
                          unsigned short* __restrict__ zwT, unsigned short* __restrict__ dwT) {
  const int zi = blockIdx.y;
  const float* src; unsigned short* dst; int R, C;
  if (zi < 3) {
    src = (zi == 0) ? zw_h : (zi == 1) ? zw_x : zw_b;
    dst = zwT + (long)zi * 65536; R = 256; C = 256;
  } else {
    int s = zi - 3, tt = s >> 2, g = s & 3;
    src = ((tt == 0) ? dw_h : (tt == 1) ? dw_x : dw_b) + (long)g * 65536;
    dst = dwT + (long)s * 65536; R = 64; C = 1024;
  }
  const int nct = C / 32;
  const int c0 = (blockIdx.x % nct) * 32, r0 = (blockIdx.x / nct) * 64;
  const int t = threadIdx.x;
  __shared__ float tile[32][66];
  #pragma unroll
  for (int p = 0; p < 8; ++p) {
    int c = t & 31, r = (t >> 5) + 8 * p;
    tile[c][r] = src[(long)(r0 + r) * C + c0 + c];
  }
  __syncthreads();
  #pragma unroll
  for (int p = 0; p < 2; ++p) {
    int kc = t & 15, cl = (t >> 4) + 16 * p;
    ushort4 o = {f2b(tile[cl][4 * kc]), f2b(tile[cl][4 * kc + 1]),
                 f2b(tile[cl][4 * kc + 2]), f2b(tile[cl][4 * kc + 3])};
    *(ushort4*)&dst[(long)(c0 + cl) * R + r0 + 4 * kc] = o;
  }
}

// ---------------- bf16 MFMA GEMM ----------------
// A: [M][K] bf16 row-major.  Bt: [N][K] bf16.  C = A @ B  [M][N]
// 4 waves 2x2; wave tile (BM/2)x(BN/2); 16x16x32 MFMA.
template <int BM, int BN>
__global__ __launch_bounds__(256, 4)
void k_gemm_bf16(const unsigned short* __restrict__ A, const unsigned short* __restrict__ Bt,
                 float* __restrict__ C, unsigned short* __restrict__ Cb,
                 const float* __restrict__ zbh, const float* __restrict__ zbx, int zepi,
                 int M, int N, int K) {
  constexpr int BK = 32;
  __shared__ __align__(16) unsigned short sA[BM * BK];
  __shared__ __align__(16) unsigned short sB[BN * BK];
  const int m0 = blockIdx.y * BM;
  const int n0 = blockIdx.x * BN;
  const int tid = threadIdx.x;
  const int wave = tid >> 6, lane = tid & 63;
  const int quad = lane >> 4, lrow = lane & 15;
  constexpr int WM = BM / 2, WN = BN / 2;
  constexpr int TM = WM / 16, TN = WN / 16;
  const int wm = (wave >> 1) * WM, wn = (wave & 1) * WN;
  constexpr int AIT = BM / 64;
  constexpr int BIT = BN / 64;

  const f32x4 vz = {0.f, 0.f, 0.f, 0.f};
  f32x4 acc[TM][TN];
  #pragma unroll
  for (int i = 0; i < TM; ++i)
    #pragma unroll
    for (int j = 0; j < TN; ++j) acc[i][j] = vz;

  for (int k0 = 0; k0 < K; k0 += BK) {
    #pragma unroll
    for (int c = 0; c < AIT; ++c) {
      int linear = c * 4096 + wave * 1024 + lane * 16;
      int row = linear >> 6, colb = linear & 63;
      const char* g = (const char*)A + ((long)(m0 + row) * K + k0) * 2 + colb;
      GLL16(g, (char*)sA + c * 4096 + wave * 1024);
    }
    #pragma unroll
    for (int c = 0; c < BIT; ++c) {
      int linear = c * 4096 + wave * 1024 + lane * 16;
      int row = linear >> 6, colb = linear & 63;
      const char* g = (const char*)Bt + ((long)(n0 + row) * K + k0) * 2 + colb;
      GLL16(g, (char*)sB + c * 4096 + wave * 1024);
    }
    __syncthreads();
    bf16x8 af[TM], bfr[TN];
    #pragma unroll
    for (int i = 0; i < TM; ++i)
      af[i] = *(const bf16x8*)&sA[(wm + i * 16 + lrow) * BK + quad * 8];
    #pragma unroll
    for (int j = 0; j < TN; ++j)
      bfr[j] = *(const bf16x8*)&sB[(wn + j * 16 + lrow) * BK + quad * 8];
    #pragma unroll
    for (int i = 0; i < TM; ++i)
      #pragma unroll
      for (int j = 0; j < TN; ++j)
        acc[i][j] = __builtin_amdgcn_mfma_f32_16x16x32_bf16(af[i], bfr[j], acc[i][j], 0, 0, 0);
    __syncthreads();
  }
  #pragma unroll
  for (int i = 0; i < TM; ++i) {
    #pragma unroll
    for (int j = 0; j < TN; ++j) {
      #pragma unroll
      for (int r = 0; r < 4; ++r) {
        int row = m0 + wm + i * 16 + quad * 4 + r;
        int col = n0 + wn + j * 16 + lrow;
        float v = acc[i][j][r];
        if (zepi) v += (col < 256) ? zbh[col] : (col < 512) ? zbx[col - 256] : 0.f;
        if (C)  C[(long)row * N + col] = v;
        if (Cb) Cb[(long)row * N + col] = f2b(v);
      }
    }
  }
}

// ---------------- hyper LSTM cell ----------------
// hg lives in Cbuf cols [4096,5120), ld=5120. hbias added here.
__global__ void k_hyper_act(const float* __restrict__ Cbuf, const float* __restrict__ hbias,
                            const float* __restrict__ chat0,
                            float* __restrict__ chat1, float* __restrict__ hhat1,
                            unsigned short* __restrict__ hhat1b) {
  int idx = blockIdx.x * 256 + threadIdx.x;        // over 2048*256
  int b = idx >> 8, zc = idx & 255;
  const float* row = Cbuf + (long)b * 5120 + 4096;
  float ih = row[zc] + hbias[zc];
  float gh = row[256 + zc] + hbias[256 + zc];
  float fh = row[512 + zc] + hbias[512 + zc];
  float oh = row[768 + zc] + hbias[768 + zc];
  float c = sigm(fh) * chat0[idx] + sigm(ih) * tanhf(gh);
  float h = sigm(oh) * tanhf(c);
  chat1[idx] = c;
  hhat1[idx] = h;
  hhat1b[idx] = f2b(h);
}

// ---------------- fused block-diag d-einsum + modulation + main cell ----------------
// block: 64 rows x 64 h-cols, loops all 4 gates x 3 types.
// z: [2048][768] bf16 (col t*256+g*64+e). dwT: slice (t*4+g) [1024][64] bf16.
// graw in Cbuf (ld 5120) cols g*1024+h.
__global__ __launch_bounds__(256, 2)
void k_dmod_lstm(const unsigned short* __restrict__ z, const unsigned short* __restrict__ dwT,
                 const float* __restrict__ Cbuf, const float* __restrict__ bias,
                 const float* __restrict__ c0, float* __restrict__ h1, float* __restrict__ c1) {
  __shared__ __align__(16) unsigned short sZ[64 * 64];
  __shared__ __align__(16) unsigned short sW[64 * 64];
  const int m0 = blockIdx.y * 64;
  const int hc0 = blockIdx.x * 64;
  const int tid = threadIdx.x, wave = tid >> 6, lane = tid & 63;
  const int quad = lane >> 4, lrow = lane & 15;
  const int wm = (wave >> 1) * 32, wn = (wave & 1) * 32;

  const f32x4 vz4 = {0.f, 0.f, 0.f, 0.f};
  f32x4 gval[4][2][2];

  for (int g = 0; g < 4; ++g) {
    f32x4 acc[3][2][2];
    #pragma unroll
    for (int t = 0; t < 3; ++t)
      #pragma unroll
      for (int i = 0; i < 2; ++i)
        #pragma unroll
        for (int j = 0; j < 2; ++j) acc[t][i][j] = vz4;

    for (int t = 0; t < 3; ++t) {
      #pragma unroll
      for (int c = 0; c < 2; ++c) {
        int linear = c * 4096 + wave * 1024 + lane * 16;  // 128B rows
        int row = linear >> 7, colb = linear & 127;
        const char* gz = (const char*)z + ((long)(m0 + row) * 768 + t * 256 + g * 64) * 2 + colb;
        GLL16(gz, (char*)sZ + c * 4096 + wave * 1024);
        const char* gw = (const char*)dwT + ((long)((t * 4 + g) * 1024 + hc0 + row) * 64) * 2 + colb;
        GLL16(gw, (char*)sW + c * 4096 + wave * 1024);
      }
      __syncthreads();
      #pragma unroll
      for (int kk = 0; kk < 2; ++kk) {
        bf16x8 za[2], wb[2];
        #pragma unroll
        for (int i = 0; i < 2; ++i)
          za[i] = *(const bf16x8*)&sZ[(wm + i * 16 + lrow) * 64 + kk * 32 + quad * 8];
        #pragma unroll
        for (int j = 0; j < 2; ++j)
          wb[j] = *(const bf16x8*)&sW[(wn + j * 16 + lrow) * 64 + kk * 32 + quad * 8];
        #pragma unroll
        for (int i = 0; i < 2; ++i)
          #pragma unroll
          for (int j = 0; j < 2; ++j)
            acc[t][i][j] = __builtin_amdgcn_mfma_f32_16x16x32_bf16(za[i], wb[j], acc[t][i][j], 0, 0, 0);
      }
      __syncthreads();
    }
    #pragma unroll
    for (int i = 0; i < 2; ++i) {
      #pragma unroll
      for (int j = 0; j < 2; ++j) {
        #pragma unroll
        for (int r = 0; r < 4; ++r) {
          int row = m0 + wm + i * 16 + quad * 4 + r;
          int col = wn + j * 16 + lrow;
          float gr = Cbuf[(long)row * 5120 + g * 1024 + hc0 + col];
          gval[g][i][j][r] = gr * acc[0][i][j][r] * acc[1][i][j][r] + acc[2][i][j][r]
                           + bias[g * 1024 + hc0 + col];
        }
      }
    }
  }
  #pragma unroll
  for (int i = 0; i < 2; ++i) {
    #pragma unroll
    for (int j = 0; j < 2; ++j) {
      #pragma unroll
      for (int r = 0; r < 4; ++r) {
        int row = m0 + wm + i * 16 + quad * 4 + r;
        int col = wn + j * 16 + lrow;
        long idx = (long)row * 1024 + hc0 + col;
        float cc = sigm(gval[2][i][j][r]) * c0[idx] + sigm(gval[0][i][j][r]) * tanhf(gval[1][i][j][r]);
        float hh = sigm(gval[3][i][j][r]) * tanhf(cc);
        c1[idx] = cc;
        h1[idx] = hh;
      }
    }
  }
}

// ---------------- launch ----------------

extern "C" void kernel_launch(void* const* d_in, const int* in_sizes, int n_in,
                              void* d_out, int out_size, void* d_ws, size_t ws_size,
                              hipStream_t stream) {
  const float* x      = (const float*)d_in[0];
  const float* h0     = (const float*)d_in[1];
  const float* c0     = (const float*)d_in[2];
  const float* hhat0  = (const float*)d_in[3];
  const float* chat0  = (const float*)d_in[4];
  const float* hweight= (const float*)d_in[5];
  const float* hbias  = (const float*)d_in[6];
  const float* zw_h   = (const float*)d_in[7];
  const float* zw_x   = (const float*)d_in[8];
  const float* zw_b   = (const float*)d_in[9];
  const float* zb_h   = (const float*)d_in[10];
  const float* zb_x   = (const float*)d_in[11];
  const float* dw_h   = (const float*)d_in[12];
  const float* dw_x   = (const float*)d_in[13];
  const float* dw_b   = (const float*)d_in[14];
  const float* weight = (const float*)d_in[15];
  const float* bias   = (const float*)d_in[16];
  float* out = (float*)d_out;

  char* w = (char*)d_ws;
  auto take = [&](size_t bytes) { char* p = w; w += (bytes + 255) & ~(size_t)255; return p; };
  unsigned short* hcatb  = (unsigned short*)take(2048ull * 2304 * 2);
  unsigned short* btc    = (unsigned short*)take(5120ull * 2304 * 2);
  unsigned short* zwT    = (unsigned short*)take(768ull * 256 * 2);
  unsigned short* dwT    = (unsigned short*)take(12ull * 1024 * 64 * 2);
  float*          Cbuf   = (float*)take(2048ull * 5120 * 4);
  unsigned short* hhat1b = (unsigned short*)take(2048ull * 256 * 2);
  unsigned short* zb16   = (unsigned short*)take(2048ull * 768 * 2);

  float* h1_o    = out;
  float* c1_o    = out + 2048 * 1024;
  float* hhat1_o = out + 2 * 2048 * 1024;
  float* chat1_o = out + 2 * 2048 * 1024 + 2048 * 256;

  // ---- prep (bf16 packs / transposes) ----
  k_pack_hcat<<<4608, 256, 0, stream>>>(hhat0, h0, x, hcatb);
  k_build_bt<<<dim3(160, 36), 256, 0, stream>>>(weight, hweight, btc);
  k_small_t<<<dim3(32, 15), 256, 0, stream>>>(zw_h, zw_x, zw_b, dw_h, dw_x, dw_b, zwT, dwT);

  // ---- combined GEMM: C[2048][5120] = hcat @ [0|W ; hW] ----
  k_gemm_bf16<64, 128><<<dim3(40, 32), 256, 0, stream>>>(
      hcatb, btc, Cbuf, nullptr, nullptr, nullptr, 0, 2048, 5120, 2304);

  // ---- hyper cell ----
  k_hyper_act<<<2048, 256, 0, stream>>>(Cbuf, hbias, chat0, chat1_o, hhat1_o, hhat1b);

  // ---- z = hhat1 @ [zw_h|zw_x|zw_b] + [zb_h|zb_x|0] (bf16) ----
  k_gemm_bf16<64, 128><<<dim3(6, 32), 256, 0, stream>>>(
      hhat1b, zwT, nullptr, zb16, zb_h, zb_x, 1, 2048, 768, 256);

  // ---- fused d-einsum + modulation + main cell ----
  k_dmod_lstm<<<dim3(16, 32), 256, 0, stream>>>(zb16, dwT, Cbuf, bias, c0, h1_o, c1_o);
}

// Round 3
// 240.960 us; speedup vs baseline: 1.3248x; 1.1368x over previous
//
#include <hip/hip_runtime.h>
#include <hip/hip_bf16.h>
#include <math.h>

// Shapes (fixed): B=2048, D=1024, H=1024, Z=256, E=64
// out = concat(h1[B,H], c1[B,H], hhat1[B,Z], chat1[B,Z]) fp32
//
// Combined bf16 GEMM C[2048][5120] = hcat[2048][2304] @ [pad|W ; hW]
//   n<4096 : gates_raw (K starts at 256 — pad region never touched), written bf16
//   n>=4096: hg (full K), written fp32
// then hyper cell -> z GEMM -> fused dmod + main cell (no scratch spills).

typedef __attribute__((ext_vector_type(8))) short bf16x8;
typedef __attribute__((ext_vector_type(4))) float f32x4;

__device__ __forceinline__ unsigned short f2b(float f) {
  union { float f; unsigned u; } v; v.f = f;
  unsigned r = v.u + 0x7fffu + ((v.u >> 16) & 1u);   // RNE
  return (unsigned short)(r >> 16);
}
__device__ __forceinline__ float b2f(unsigned short b) {
  union { unsigned u; float f; } v; v.u = ((unsigned)b) << 16; return v.f;
}
__device__ __forceinline__ float sigm(float x) { return 1.f / (1.f + __expf(-x)); }

#define GLL16(gsrc, ldst)                                                      \
  __builtin_amdgcn_global_load_lds(                                            \
      (const __attribute__((address_space(1))) void*)(gsrc),                   \
      (__attribute__((address_space(3))) void*)(ldst), 16, 0, 0)

// ---------------- pack hcat = [hhat0|h0|x] -> bf16 [2048][2304] ----------------
__global__ void k_pack_hcat(const float* __restrict__ hhat0, const float* __restrict__ h0,
                            const float* __restrict__ x, unsigned short* __restrict__ out) {
  int i = blockIdx.x * 256 + threadIdx.x;          // over 2048*576 float4s
  int b = i / 576, c4 = i % 576;
  const float* src;
  if (c4 < 64)       src = hhat0 + (long)b * 256 + c4 * 4;
  else if (c4 < 320) src = h0 + (long)b * 1024 + (c4 - 64) * 4;
  else               src = x + (long)b * 1024 + (c4 - 320) * 4;
  float4 v = *(const float4*)src;
  ushort4 o = {f2b(v.x), f2b(v.y), f2b(v.z), f2b(v.w)};
  *(ushort4*)&out[(long)b * 2304 + c4 * 4] = o;
}

// ---------------- build combined Bt [5120][2304] bf16 ----------------
// n<4096, k>=256 -> weight[k-256][n].  n>=4096 -> hweight[k][n-4096].
// (n<4096, k<256 region is never read by the GEMM -> not written.)
__global__ void k_build_bt(const float* __restrict__ weight, const float* __restrict__ hweight,
                           unsigned short* __restrict__ bt) {
  const int n0 = blockIdx.x * 32, k0 = blockIdx.y * 64;
  if (n0 < 4096 && k0 < 256) return;
  const int t = threadIdx.x;
  __shared__ float tile[32][66];
  const float* src; int C, sc0, sr0;
  if (n0 >= 4096) { src = hweight; C = 1024; sc0 = n0 - 4096; sr0 = k0; }
  else            { src = weight;  C = 4096; sc0 = n0;        sr0 = k0 - 256; }
  #pragma unroll
  for (int p = 0; p < 8; ++p) {
    int c = t & 31, r = (t >> 5) + 8 * p;
    tile[c][r] = src[(long)(sr0 + r) * C + sc0 + c];
  }
  __syncthreads();
  #pragma unroll
  for (int p = 0; p < 2; ++p) {
    int kc = t & 15, cl = (t >> 4) + 16 * p;
    ushort4 o = {f2b(tile[cl][4 * kc]), f2b(tile[cl][4 * kc + 1]),
                 f2b(tile[cl][4 * kc + 2]), f2b(tile[cl][4 * kc + 3])};
    *(ushort4*)&bt[(long)(n0 + cl) * 2304 + k0 + 4 * kc] = o;
  }
}

// ---------------- small transposes: zwT (3x 256x256) + dwT (12x 64x1024 -> 1024x64) ----
__global__ void k_small_t(const float* __restrict__ zw_h, const float* __restrict__ zw_x,
                          const float* __restrict__ zw_b, const float* __restrict__ dw_h,
                          const float* __restrict__ dw_x, const float* __restrict__ dw_b,
                          unsigned short* __restrict__ zwT, unsigned short* __restrict__ dwT) {
  const int zi = blockIdx.y;
  const float* src; unsigned short* dst; int R, C;
  if (zi < 3) {
    src = (zi == 0) ? zw_h : (zi == 1) ? zw_x : zw_b;
    dst = zwT + (long)zi * 65536; R = 256; C = 256;
  } else {
    int s = zi - 3, tt = s >> 2, g = s & 3;
    src = ((tt == 0) ? dw_h : (tt == 1) ? dw_x : dw_b) + (long)g * 65536;
    dst = dwT + (long)s * 65536; R = 64; C = 1024;
  }
  const int nct = C / 32;
  const int c0 = (blockIdx.x % nct) * 32, r0 = (blockIdx.x / nct) * 64;
  const int t = threadIdx.x;
  __shared__ float tile[32][66];
  #pragma unroll
  for (int p = 0; p < 8; ++p) {
    int c = t & 31, r = (t >> 5) + 8 * p;
    tile[c][r] = src[(long)(r0 + r) * C + c0 + c];
  }
  __syncthreads();
  #pragma unroll
  for (int p = 0; p < 2; ++p) {
    int kc = t & 15, cl = (t >> 4) + 16 * p;
    ushort4 o = {f2b(tile[cl][4 * kc]), f2b(tile[cl][4 * kc + 1]),
                 f2b(tile[cl][4 * kc + 2]), f2b(tile[cl][4 * kc + 3])};
    *(ushort4*)&dst[(long)(c0 + cl) * R + r0 + 4 * kc] = o;
  }
}

// ---------------- bf16 MFMA GEMM ----------------
// A [M][K] bf16, Bt [N][K] bf16. mode 0: combined epilogue (bf16 graw / fp32 hg).
// mode 1: bf16 out + zbias.  Blocks with n0 < nsplit start K at 256.
template <int BM, int BN>
__global__ __launch_bounds__(256, 2)
void k_gemm_bf16(const unsigned short* __restrict__ A, const unsigned short* __restrict__ Bt,
                 int M, int N, int K, int nsplit, int mode,
                 float* __restrict__ hgbuf, unsigned short* __restrict__ grawb,
                 unsigned short* __restrict__ zbout,
                 const float* __restrict__ zbh, const float* __restrict__ zbx) {
  constexpr int BK = 32;
  __shared__ __align__(16) unsigned short sA[BM * BK];
  __shared__ __align__(16) unsigned short sB[BN * BK];
  const int m0 = blockIdx.y * BM;
  const int n0 = blockIdx.x * BN;
  const int kstart = (n0 < nsplit) ? 256 : 0;
  const int tid = threadIdx.x;
  const int wave = tid >> 6, lane = tid & 63;
  const int quad = lane >> 4, lrow = lane & 15;
  constexpr int WM = BM / 2, WN = BN / 2;
  constexpr int TM = WM / 16, TN = WN / 16;
  const int wm = (wave >> 1) * WM, wn = (wave & 1) * WN;
  constexpr int AIT = BM / 64;
  constexpr int BIT = BN / 64;

  const f32x4 vz = {0.f, 0.f, 0.f, 0.f};
  f32x4 acc[TM][TN];
  #pragma unroll
  for (int i = 0; i < TM; ++i)
    #pragma unroll
    for (int j = 0; j < TN; ++j) acc[i][j] = vz;

  for (int k0 = kstart; k0 < K; k0 += BK) {
    #pragma unroll
    for (int c = 0; c < AIT; ++c) {
      int linear = c * 4096 + wave * 1024 + lane * 16;
      int row = linear >> 6, colb = linear & 63;
      const char* g = (const char*)A + ((long)(m0 + row) * K + k0) * 2 + colb;
      GLL16(g, (char*)sA + c * 4096 + wave * 1024);
    }
    #pragma unroll
    for (int c = 0; c < BIT; ++c) {
      int linear = c * 4096 + wave * 1024 + lane * 16;
      int row = linear >> 6, colb = linear & 63;
      const char* g = (const char*)Bt + ((long)(n0 + row) * K + k0) * 2 + colb;
      GLL16(g, (char*)sB + c * 4096 + wave * 1024);
    }
    __syncthreads();
    bf16x8 af[TM], bfr[TN];
    #pragma unroll
    for (int i = 0; i < TM; ++i)
      af[i] = *(const bf16x8*)&sA[(wm + i * 16 + lrow) * BK + quad * 8];
    #pragma unroll
    for (int j = 0; j < TN; ++j)
      bfr[j] = *(const bf16x8*)&sB[(wn + j * 16 + lrow) * BK + quad * 8];
    #pragma unroll
    for (int i = 0; i < TM; ++i)
      #pragma unroll
      for (int j = 0; j < TN; ++j)
        acc[i][j] = __builtin_amdgcn_mfma_f32_16x16x32_bf16(af[i], bfr[j], acc[i][j], 0, 0, 0);
    __syncthreads();
  }
  #pragma unroll
  for (int i = 0; i < TM; ++i) {
    #pragma unroll
    for (int j = 0; j < TN; ++j) {
      #pragma unroll
      for (int r = 0; r < 4; ++r) {
        int row = m0 + wm + i * 16 + quad * 4 + r;
        int col = n0 + wn + j * 16 + lrow;
        float v = acc[i][j][r];
        if (mode == 0) {
          if (col < 4096) grawb[(long)row * 4096 + col] = f2b(v);
          else            hgbuf[(long)row * 1024 + (col - 4096)] = v;
        } else {
          v += (col < 256) ? zbh[col] : (col < 512) ? zbx[col - 256] : 0.f;
          zbout[(long)row * N + col] = f2b(v);
        }
      }
    }
  }
}

// ---------------- hyper LSTM cell ----------------
__global__ void k_hyper_act(const float* __restrict__ hgbuf, const float* __restrict__ hbias,
                            const float* __restrict__ chat0,
                            float* __restrict__ chat1, float* __restrict__ hhat1,
                            unsigned short* __restrict__ hhat1b) {
  int idx = blockIdx.x * 256 + threadIdx.x;        // over 2048*256
  int b = idx >> 8, zc = idx & 255;
  const float* row = hgbuf + (long)b * 1024;
  float ih = row[zc] + hbias[zc];
  float gh = row[256 + zc] + hbias[256 + zc];
  float fh = row[512 + zc] + hbias[512 + zc];
  float oh = row[768 + zc] + hbias[768 + zc];
  float c = sigm(fh) * chat0[idx] + sigm(ih) * tanhf(gh);
  float h = sigm(oh) * tanhf(c);
  chat1[idx] = c;
  hhat1[idx] = h;
  hhat1b[idx] = f2b(h);
}

// ---------------- fused d-einsum + modulation + main cell ----------------
// One MFMA stage: load z(t,g)/dw(t,g) tiles into LDS, accumulate 64x64 wave-tiles.
// acc is statically indexed everywhere -> stays in registers (no scratch).
__device__ __forceinline__ void dmod_stage(
    const unsigned short* __restrict__ z, const unsigned short* __restrict__ dwT,
    unsigned short* sZ, unsigned short* sW, int m0, int hc0, int g, int t,
    int wave, int lane, int wm, int wn, int quad, int lrow, f32x4 acc[2][2]) {
  #pragma unroll
  for (int c = 0; c < 2; ++c) {
    int linear = c * 4096 + wave * 1024 + lane * 16;  // 128B rows
    int row = linear >> 7, colb = linear & 127;
    const char* gz = (const char*)z + ((long)(m0 + row) * 768 + t * 256 + g * 64) * 2 + colb;
    GLL16(gz, (char*)sZ + c * 4096 + wave * 1024);
    const char* gw = (const char*)dwT + ((long)((t * 4 + g) * 1024 + hc0 + row) * 64) * 2 + colb;
    GLL16(gw, (char*)sW + c * 4096 + wave * 1024);
  }
  __syncthreads();
  #pragma unroll
  for (int kk = 0; kk < 2; ++kk) {
    bf16x8 za[2], wb[2];
    #pragma unroll
    for (int i = 0; i < 2; ++i)
      za[i] = *(const bf16x8*)&sZ[(wm + i * 16 + lrow) * 64 + kk * 32 + quad * 8];
    #pragma unroll
    for (int j = 0; j < 2; ++j)
      wb[j] = *(const bf16x8*)&sW[(wn + j * 16 + lrow) * 64 + kk * 32 + quad * 8];
    #pragma unroll
    for (int i = 0; i < 2; ++i)
      #pragma unroll
      for (int j = 0; j < 2; ++j)
        acc[i][j] = __builtin_amdgcn_mfma_f32_16x16x32_bf16(za[i], wb[j], acc[i][j], 0, 0, 0);
  }
  __syncthreads();
}

__global__ __launch_bounds__(256, 2)
void k_dmod_lstm(const unsigned short* __restrict__ z, const unsigned short* __restrict__ dwT,
                 const unsigned short* __restrict__ grawb, const float* __restrict__ bias,
                 const float* __restrict__ c0, float* __restrict__ h1, float* __restrict__ c1) {
  __shared__ __align__(16) unsigned short sZ[64 * 64];
  __shared__ __align__(16) unsigned short sW[64 * 64];
  const int m0 = blockIdx.y * 64;
  const int hc0 = blockIdx.x * 64;
  const int tid = threadIdx.x, wave = tid >> 6, lane = tid & 63;
  const int quad = lane >> 4, lrow = lane & 15;
  const int wm = (wave >> 1) * 32, wn = (wave & 1) * 32;
  const f32x4 vz4 = {0.f, 0.f, 0.f, 0.f};

  f32x4 pcar[2][2];   // progressive carry: sigm(i) -> sigm(i)*tanh(g)
  f32x4 ccar[2][2];   // c1

  #pragma unroll
  for (int g = 0; g < 4; ++g) {
    f32x4 aH[2][2], aX[2][2], aB[2][2];
    #pragma unroll
    for (int i = 0; i < 2; ++i)
      #pragma unroll
      for (int j = 0; j < 2; ++j) { aH[i][j] = vz4; aX[i][j] = vz4; aB[i][j] = vz4; }

    dmod_stage(z, dwT, sZ, sW, m0, hc0, g, 0, wave, lane, wm, wn, quad, lrow, aH);
    dmod_stage(z, dwT, sZ, sW, m0, hc0, g, 1, wave, lane, wm, wn, quad, lrow, aX);
    dmod_stage(z, dwT, sZ, sW, m0, hc0, g, 2, wave, lane, wm, wn, quad, lrow, aB);

    #pragma unroll
    for (int i = 0; i < 2; ++i) {
      #pragma unroll
      for (int j = 0; j < 2; ++j) {
        #pragma unroll
        for (int r = 0; r < 4; ++r) {
          int row = m0 + wm + i * 16 + quad * 4 + r;
          int col = wn + j * 16 + lrow;
          float gr = b2f(grawb[(long)row * 4096 + g * 1024 + hc0 + col]);
          float v = gr * aH[i][j][r] * aX[i][j][r] + aB[i][j][r] + bias[g * 1024 + hc0 + col];
          long idx = (long)row * 1024 + hc0 + col;
          if (g == 0) pcar[i][j][r] = sigm(v);
          else if (g == 1) pcar[i][j][r] *= tanhf(v);
          else if (g == 2) {
            float cc = sigm(v) * c0[idx] + pcar[i][j][r];
            ccar[i][j][r] = cc;
            c1[idx] = cc;
          } else {
            h1[idx] = sigm(v) * tanhf(ccar[i][j][r]);
          }
        }
      }
    }
  }
}

// ---------------- launch ----------------

extern "C" void kernel_launch(void* const* d_in, const int* in_sizes, int n_in,
                              void* d_out, int out_size, void* d_ws, size_t ws_size,
                              hipStream_t stream) {
  const float* x      = (const float*)d_in[0];
  const float* h0     = (const float*)d_in[1];
  const float* c0     = (const float*)d_in[2];
  const float* hhat0  = (const float*)d_in[3];
  const float* chat0  = (const float*)d_in[4];
  const float* hweight= (const float*)d_in[5];
  const float* hbias  = (const float*)d_in[6];
  const float* zw_h   = (const float*)d_in[7];
  const float* zw_x   = (const float*)d_in[8];
  const float* zw_b   = (const float*)d_in[9];
  const float* zb_h   = (const float*)d_in[10];
  const float* zb_x   = (const float*)d_in[11];
  const float* dw_h   = (const float*)d_in[12];
  const float* dw_x   = (const float*)d_in[13];
  const float* dw_b   = (const float*)d_in[14];
  const float* weight = (const float*)d_in[15];
  const float* bias   = (const float*)d_in[16];
  float* out = (float*)d_out;

  char* w = (char*)d_ws;
  auto take = [&](size_t bytes) { char* p = w; w += (bytes + 255) & ~(size_t)255; return p; };
  unsigned short* hcatb  = (unsigned short*)take(2048ull * 2304 * 2);
  unsigned short* btc    = (unsigned short*)take(5120ull * 2304 * 2);
  unsigned short* zwT    = (unsigned short*)take(768ull * 256 * 2);
  unsigned short* dwT    = (unsigned short*)take(12ull * 1024 * 64 * 2);
  unsigned short* grawb  = (unsigned short*)take(2048ull * 4096 * 2);
  float*          hgbuf  = (float*)take(2048ull * 1024 * 4);
  unsigned short* hhat1b = (unsigned short*)take(2048ull * 256 * 2);
  unsigned short* zb16   = (unsigned short*)take(2048ull * 768 * 2);

  float* h1_o    = out;
  float* c1_o    = out + 2048 * 1024;
  float* hhat1_o = out + 2 * 2048 * 1024;
  float* chat1_o = out + 2 * 2048 * 1024 + 2048 * 256;

  // ---- prep ----
  k_pack_hcat<<<4608, 256, 0, stream>>>(hhat0, h0, x, hcatb);
  k_build_bt<<<dim3(160, 36), 256, 0, stream>>>(weight, hweight, btc);
  k_small_t<<<dim3(32, 15), 256, 0, stream>>>(zw_h, zw_x, zw_b, dw_h, dw_x, dw_b, zwT, dwT);

  // ---- combined GEMM: [graw bf16 | hg fp32] ----
  k_gemm_bf16<128, 128><<<dim3(40, 16), 256, 0, stream>>>(
      hcatb, btc, 2048, 5120, 2304, 4096, 0, hgbuf, grawb, nullptr, nullptr, nullptr);

  // ---- hyper cell ----
  k_hyper_act<<<2048, 256, 0, stream>>>(hgbuf, hbias, chat0, chat1_o, hhat1_o, hhat1b);

  // ---- z = hhat1 @ [zw_h|zw_x|zw_b] + [zb_h|zb_x|0] (bf16) ----
  k_gemm_bf16<64, 128><<<dim3(6, 32), 256, 0, stream>>>(
      hhat1b, zwT, 2048, 768, 256, 0, 1, nullptr, nullptr, zb16, zb_h, zb_x);

  // ---- fused d-einsum + modulation + main cell ----
  k_dmod_lstm<<<dim3(16, 32), 256, 0, stream>>>(zb16, dwT, grawb, bias, c0, h1_o, c1_o);
}

// Round 4
// 230.805 us; speedup vs baseline: 1.3830x; 1.0440x over previous
//
#include <hip/hip_runtime.h>
#include <hip/hip_bf16.h>
#include <math.h>

// Shapes (fixed): B=2048, D=1024, H=1024, Z=256, E=64
// out = concat(h1[B,H], c1[B,H], hhat1[B,Z], chat1[B,Z]) fp32
//
// Pipeline (5 launches):
//  1. k_prep      : pack hcat bf16 + build combined Bt + small transposes
//  2. k_gemm_main : C[2048][5120] = hcat @ [pad|W ; hW]  (512 thr, swizzled LDS)
//  3. k_hyper_act : hyper LSTM cell -> hhat1/chat1 (+ bf16 hhat1)
//  4. k_gemm_z    : z = hhat1 @ [zw_h|zw_x|zw_b] + bias   (bf16 out)
//  5. k_dmod_lstm : block-diag d-einsum + modulation + main LSTM cell

typedef __attribute__((ext_vector_type(8))) short bf16x8;
typedef __attribute__((ext_vector_type(4))) float f32x4;
typedef unsigned short u16;

__device__ __forceinline__ u16 f2b(float f) {
  union { float f; unsigned u; } v; v.f = f;
  unsigned r = v.u + 0x7fffu + ((v.u >> 16) & 1u);   // RNE
  return (u16)(r >> 16);
}
__device__ __forceinline__ float b2f(u16 b) {
  union { unsigned u; float f; } v; v.u = ((unsigned)b) << 16; return v.f;
}
__device__ __forceinline__ float sigm(float x) { return 1.f / (1.f + __expf(-x)); }

#define GLL16(gsrc, ldst)                                                      \
  __builtin_amdgcn_global_load_lds(                                            \
      (const __attribute__((address_space(1))) void*)(gsrc),                   \
      (__attribute__((address_space(3))) void*)(ldst), 16, 0, 0)

// ---------------- merged prep ----------------
// blocks [0,4608)            : pack hcat = [hhat0|h0|x] -> bf16 [2048][2304]
// blocks [4608, 4608+5760)   : build Bt [5120][2304] (skip n<4096,k<256 pad)
// blocks [10368, 10368+480)  : zwT (3x 256x256) + dwT (12x 64x1024 -> 1024x64)
__global__ void k_prep(const float* __restrict__ hhat0, const float* __restrict__ h0,
                       const float* __restrict__ x, const float* __restrict__ weight,
                       const float* __restrict__ hweight,
                       const float* __restrict__ zw_h, const float* __restrict__ zw_x,
                       const float* __restrict__ zw_b, const float* __restrict__ dw_h,
                       const float* __restrict__ dw_x, const float* __restrict__ dw_b,
                       u16* __restrict__ hcatb, u16* __restrict__ bt,
                       u16* __restrict__ zwT, u16* __restrict__ dwT) {
  __shared__ float tile[32][66];
  int bid = blockIdx.x;
  const int t = threadIdx.x;
  if (bid < 4608) {
    int i = bid * 256 + t;                 // over 2048*576 float4s
    int b = i / 576, c4 = i % 576;
    const float* src;
    if (c4 < 64)       src = hhat0 + (long)b * 256 + c4 * 4;
    else if (c4 < 320) src = h0 + (long)b * 1024 + (c4 - 64) * 4;
    else               src = x + (long)b * 1024 + (c4 - 320) * 4;
    float4 v = *(const float4*)src;
    ushort4 o = {f2b(v.x), f2b(v.y), f2b(v.z), f2b(v.w)};
    *(ushort4*)&hcatb[(long)b * 2304 + c4 * 4] = o;
    return;
  }
  bid -= 4608;
  if (bid < 5760) {                        // build Bt
    const int n0 = (bid % 160) * 32, k0 = (bid / 160) * 64;
    if (n0 < 4096 && k0 < 256) return;
    const float* src; int C, sc0, sr0;
    if (n0 >= 4096) { src = hweight; C = 1024; sc0 = n0 - 4096; sr0 = k0; }
    else            { src = weight;  C = 4096; sc0 = n0;        sr0 = k0 - 256; }
    #pragma unroll
    for (int p = 0; p < 8; ++p) {
      int c = t & 31, r = (t >> 5) + 8 * p;
      tile[c][r] = src[(long)(sr0 + r) * C + sc0 + c];
    }
    __syncthreads();
    #pragma unroll
    for (int p = 0; p < 2; ++p) {
      int kc = t & 15, cl = (t >> 4) + 16 * p;
      ushort4 o = {f2b(tile[cl][4 * kc]), f2b(tile[cl][4 * kc + 1]),
                   f2b(tile[cl][4 * kc + 2]), f2b(tile[cl][4 * kc + 3])};
      *(ushort4*)&bt[(long)(n0 + cl) * 2304 + k0 + 4 * kc] = o;
    }
    return;
  }
  bid -= 5760;                             // small transposes
  const int zi = bid >> 5, bx = bid & 31;
  const float* src; u16* dst; int R, C;
  if (zi < 3) {
    src = (zi == 0) ? zw_h : (zi == 1) ? zw_x : zw_b;
    dst = zwT + (long)zi * 65536; R = 256; C = 256;
  } else {
    int s = zi - 3, tt = s >> 2, g = s & 3;
    src = ((tt == 0) ? dw_h : (tt == 1) ? dw_x : dw_b) + (long)g * 65536;
    dst = dwT + (long)s * 65536; R = 64; C = 1024;
  }
  const int nct = C / 32;
  const int c0 = (bx % nct) * 32, r0 = (bx / nct) * 64;
  #pragma unroll
  for (int p = 0; p < 8; ++p) {
    int c = t & 31, r = (t >> 5) + 8 * p;
    tile[c][r] = src[(long)(r0 + r) * C + c0 + c];
  }
  __syncthreads();
  #pragma unroll
  for (int p = 0; p < 2; ++p) {
    int kc = t & 15, cl = (t >> 4) + 16 * p;
    ushort4 o = {f2b(tile[cl][4 * kc]), f2b(tile[cl][4 * kc + 1]),
                 f2b(tile[cl][4 * kc + 2]), f2b(tile[cl][4 * kc + 3])};
    *(ushort4*)&dst[(long)(c0 + cl) * R + r0 + 4 * kc] = o;
  }
}

// ---------------- main GEMM: 512 threads, 128x128 tile, swizzled LDS ----------------
// A [2048][2304] bf16, Bt [5120][2304] bf16.  n<4096 -> kstart=256, bf16 out (grawb);
// n>=4096 -> full K, fp32 out (hgbuf).
__global__ __launch_bounds__(512, 4)
void k_gemm_main(const u16* __restrict__ A, const u16* __restrict__ Bt,
                 float* __restrict__ hgbuf, u16* __restrict__ grawb) {
  constexpr int K = 2304, BK = 32;
  __shared__ __align__(16) u16 sA[128 * BK];
  __shared__ __align__(16) u16 sB[128 * BK];
  const int m0 = blockIdx.y * 128, n0 = blockIdx.x * 128;
  const int kstart = (n0 < 4096) ? 256 : 0;
  const int tid = threadIdx.x, wave = tid >> 6, lane = tid & 63;
  const int quad = lane >> 4, lrow = lane & 15;
  const int wm = (wave >> 2) * 64, wn = (wave & 3) * 32;

  // staging: 8KB tile per operand, one GLL16 per thread. Swizzle: phys chunk p
  // of row r holds logical chunk q = (p - (r>>1)) & 3.
  const int sl = tid * 16;
  const int srow = sl >> 6;
  const int sq = (((sl & 63) >> 4) - (srow >> 1)) & 3;
  const long aoff = ((long)(m0 + srow) * K) * 2 + sq * 16;
  const long boff = ((long)(n0 + srow) * K) * 2 + sq * 16;

  const f32x4 vz = {0.f, 0.f, 0.f, 0.f};
  f32x4 acc[4][2];
  #pragma unroll
  for (int i = 0; i < 4; ++i)
    #pragma unroll
    for (int j = 0; j < 2; ++j) acc[i][j] = vz;

  for (int k0 = kstart; k0 < K; k0 += BK) {
    GLL16((const char*)A + aoff + (long)k0 * 2, (char*)sA + wave * 1024);
    GLL16((const char*)Bt + boff + (long)k0 * 2, (char*)sB + wave * 1024);
    __syncthreads();
    bf16x8 af[4], bf[2];
    #pragma unroll
    for (int i = 0; i < 4; ++i) {
      int row = wm + i * 16 + lrow;
      af[i] = *(const bf16x8*)((const char*)sA + row * 64 + (((quad + (row >> 1)) & 3) << 4));
    }
    #pragma unroll
    for (int j = 0; j < 2; ++j) {
      int row = wn + j * 16 + lrow;
      bf[j] = *(const bf16x8*)((const char*)sB + row * 64 + (((quad + (row >> 1)) & 3) << 4));
    }
    #pragma unroll
    for (int i = 0; i < 4; ++i)
      #pragma unroll
      for (int j = 0; j < 2; ++j)
        acc[i][j] = __builtin_amdgcn_mfma_f32_16x16x32_bf16(af[i], bf[j], acc[i][j], 0, 0, 0);
    __syncthreads();
  }
  #pragma unroll
  for (int i = 0; i < 4; ++i) {
    #pragma unroll
    for (int j = 0; j < 2; ++j) {
      #pragma unroll
      for (int r = 0; r < 4; ++r) {
        int row = m0 + wm + i * 16 + quad * 4 + r;
        int col = n0 + wn + j * 16 + lrow;
        float v = acc[i][j][r];
        if (col < 4096) grawb[(long)row * 4096 + col] = f2b(v);
        else            hgbuf[(long)row * 1024 + (col - 4096)] = v;
      }
    }
  }
}

// ---------------- z GEMM: 256 threads, 64x128 tile ----------------
// A = hhat1b [2048][256], Bt = zwT [768][256]. out bf16 zb16 [2048][768] + zbias.
__global__ __launch_bounds__(256, 2)
void k_gemm_z(const u16* __restrict__ A, const u16* __restrict__ Bt,
              const float* __restrict__ zbh, const float* __restrict__ zbx,
              u16* __restrict__ zbout) {
  constexpr int K = 256, BK = 32;
  __shared__ __align__(16) u16 sA[64 * BK];
  __shared__ __align__(16) u16 sB[128 * BK];
  const int m0 = blockIdx.y * 64, n0 = blockIdx.x * 128;
  const int tid = threadIdx.x, wave = tid >> 6, lane = tid & 63;
  const int quad = lane >> 4, lrow = lane & 15;
  const int wm = (wave >> 1) * 32, wn = (wave & 1) * 64;

  const int sl = tid * 16;
  const int arow = sl >> 6;
  const int aq = (((sl & 63) >> 4) - (arow >> 1)) & 3;
  const long aoff = ((long)(m0 + arow) * K) * 2 + aq * 16;

  const f32x4 vz = {0.f, 0.f, 0.f, 0.f};
  f32x4 acc[2][4];
  #pragma unroll
  for (int i = 0; i < 2; ++i)
    #pragma unroll
    for (int j = 0; j < 4; ++j) acc[i][j] = vz;

  for (int k0 = 0; k0 < K; k0 += BK) {
    GLL16((const char*)A + aoff + (long)k0 * 2, (char*)sA + wave * 1024);
    #pragma unroll
    for (int c = 0; c < 2; ++c) {
      int l = c * 4096 + sl;
      int row = l >> 6;
      int q = (((l & 63) >> 4) - (row >> 1)) & 3;
      const char* g = (const char*)Bt + ((long)(n0 + row) * K + k0) * 2 + q * 16;
      GLL16(g, (char*)sB + c * 4096 + wave * 1024);
    }
    __syncthreads();
    bf16x8 af[2], bf[4];
    #pragma unroll
    for (int i = 0; i < 2; ++i) {
      int row = wm + i * 16 + lrow;
      af[i] = *(const bf16x8*)((const char*)sA + row * 64 + (((quad + (row >> 1)) & 3) << 4));
    }
    #pragma unroll
    for (int j = 0; j < 4; ++j) {
      int row = wn + j * 16 + lrow;
      bf[j] = *(const bf16x8*)((const char*)sB + row * 64 + (((quad + (row >> 1)) & 3) << 4));
    }
    #pragma unroll
    for (int i = 0; i < 2; ++i)
      #pragma unroll
      for (int j = 0; j < 4; ++j)
        acc[i][j] = __builtin_amdgcn_mfma_f32_16x16x32_bf16(af[i], bf[j], acc[i][j], 0, 0, 0);
    __syncthreads();
  }
  #pragma unroll
  for (int i = 0; i < 2; ++i) {
    #pragma unroll
    for (int j = 0; j < 4; ++j) {
      #pragma unroll
      for (int r = 0; r < 4; ++r) {
        int row = m0 + wm + i * 16 + quad * 4 + r;
        int col = n0 + wn + j * 16 + lrow;
        float v = acc[i][j][r] + ((col < 256) ? zbh[col] : (col < 512) ? zbx[col - 256] : 0.f);
        zbout[(long)row * 768 + col] = f2b(v);
      }
    }
  }
}

// ---------------- hyper LSTM cell ----------------
__global__ void k_hyper_act(const float* __restrict__ hgbuf, const float* __restrict__ hbias,
                            const float* __restrict__ chat0,
                            float* __restrict__ chat1, float* __restrict__ hhat1,
                            u16* __restrict__ hhat1b) {
  int idx = blockIdx.x * 256 + threadIdx.x;        // over 2048*256
  int b = idx >> 8, zc = idx & 255;
  const float* row = hgbuf + (long)b * 1024;
  float ih = row[zc] + hbias[zc];
  float gh = row[256 + zc] + hbias[256 + zc];
  float fh = row[512 + zc] + hbias[512 + zc];
  float oh = row[768 + zc] + hbias[768 + zc];
  float c = sigm(fh) * chat0[idx] + sigm(ih) * tanhf(gh);
  float h = sigm(oh) * tanhf(c);
  chat1[idx] = c;
  hhat1[idx] = h;
  hhat1b[idx] = f2b(h);
}

// ---------------- fused d-einsum + modulation + main cell ----------------
// Per gate: one staging phase loads z strips (64 rows x 3x64 cols) and the 3 dwT
// slices (3 x 64 rows x 64), then 3 MFMA chains (aH/aX/aB). 8 barriers total.
// LDS swizzles: sZ phys chunk (of 24/row) = (q + row) % 24; sW (of 8/row) = (q + row) & 7.
__global__ __launch_bounds__(256, 2)
void k_dmod_lstm(const u16* __restrict__ z, const u16* __restrict__ dwT,
                 const u16* __restrict__ grawb, const float* __restrict__ bias,
                 const float* __restrict__ c0, float* __restrict__ h1,
                 float* __restrict__ c1) {
  __shared__ __align__(16) u16 sZ[64 * 192];   // 24576 B
  __shared__ __align__(16) u16 sW[3 * 64 * 64];// 24576 B
  const int m0 = blockIdx.y * 64;
  const int hc0 = blockIdx.x * 64;
  const int tid = threadIdx.x, wave = tid >> 6, lane = tid & 63;
  const int quad = lane >> 4, lrow = lane & 15;
  const int wm = (wave >> 1) * 32, wn = (wave & 1) * 32;
  const f32x4 vz4 = {0.f, 0.f, 0.f, 0.f};

  f32x4 pcar[2][2];   // progressive carry: sigm(i) -> sigm(i)*tanh(g)
  f32x4 ccar[2][2];   // c1

  #pragma unroll
  for (int g = 0; g < 4; ++g) {
    // ---- stage ----
    #pragma unroll
    for (int c = 0; c < 6; ++c) {
      int l = c * 4096 + tid * 16;
      // sZ: rows of 24 chunks
      int ci = l >> 4, row = ci / 24, p = ci - row * 24;
      int q = p + 72 - row; q -= (q / 24) * 24;            // (p - row) mod 24
      int tt = q >> 3, e16 = q & 7;
      const char* gz = (const char*)z + (long)(m0 + row) * 1536 + tt * 512 + g * 128 + e16 * 16;
      GLL16(gz, (char*)sZ + c * 4096 + wave * 1024);
      // sW: 3 slices of 64 rows x 8 chunks
      int t2 = l >> 13, rw = (l & 8191) >> 7, p2 = (l >> 4) & 7;
      int q2 = (p2 - rw) & 7;
      const char* gw = (const char*)dwT + (long)((t2 * 4 + g) * 1024 + hc0 + rw) * 128 + q2 * 16;
      GLL16(gw, (char*)sW + c * 4096 + wave * 1024);
    }
    __syncthreads();
    // ---- MFMA ----
    f32x4 aH[2][2], aX[2][2], aB[2][2];
    #pragma unroll
    for (int i = 0; i < 2; ++i)
      #pragma unroll
      for (int j = 0; j < 2; ++j) { aH[i][j] = vz4; aX[i][j] = vz4; aB[i][j] = vz4; }
    #pragma unroll
    for (int kk = 0; kk < 2; ++kk) {
      bf16x8 za[3][2], wb[3][2];
      #pragma unroll
      for (int t = 0; t < 3; ++t) {
        #pragma unroll
        for (int i = 0; i < 2; ++i) {
          int row = wm + i * 16 + lrow;
          int q0 = t * 8 + kk * 4 + quad;
          int ph = q0 + row; ph -= (ph / 24) * 24;
          za[t][i] = *(const bf16x8*)((const char*)sZ + row * 384 + ph * 16);
        }
        #pragma unroll
        for (int j = 0; j < 2; ++j) {
          int row = wn + j * 16 + lrow;
          int q0 = kk * 4 + quad;
          int ph = (q0 + row) & 7;
          wb[t][j] = *(const bf16x8*)((const char*)sW + t * 8192 + row * 128 + ph * 16);
        }
      }
      #pragma unroll
      for (int i = 0; i < 2; ++i)
        #pragma unroll
        for (int j = 0; j < 2; ++j) {
          aH[i][j] = __builtin_amdgcn_mfma_f32_16x16x32_bf16(za[0][i], wb[0][j], aH[i][j], 0, 0, 0);
          aX[i][j] = __builtin_amdgcn_mfma_f32_16x16x32_bf16(za[1][i], wb[1][j], aX[i][j], 0, 0, 0);
          aB[i][j] = __builtin_amdgcn_mfma_f32_16x16x32_bf16(za[2][i], wb[2][j], aB[i][j], 0, 0, 0);
        }
    }
    __syncthreads();
    // ---- per-gate epilogue ----
    #pragma unroll
    for (int i = 0; i < 2; ++i) {
      #pragma unroll
      for (int j = 0; j < 2; ++j) {
        #pragma unroll
        for (int r = 0; r < 4; ++r) {
          int row = m0 + wm + i * 16 + quad * 4 + r;
          int col = wn + j * 16 + lrow;
          float gr = b2f(grawb[(long)row * 4096 + g * 1024 + hc0 + col]);
          float v = gr * aH[i][j][r] * aX[i][j][r] + aB[i][j][r] + bias[g * 1024 + hc0 + col];
          long idx = (long)row * 1024 + hc0 + col;
          if (g == 0) pcar[i][j][r] = sigm(v);
          else if (g == 1) pcar[i][j][r] *= tanhf(v);
          else if (g == 2) {
            float cc = sigm(v) * c0[idx] + pcar[i][j][r];
            ccar[i][j][r] = cc;
            c1[idx] = cc;
          } else {
            h1[idx] = sigm(v) * tanhf(ccar[i][j][r]);
          }
        }
      }
    }
  }
}

// ---------------- launch ----------------

extern "C" void kernel_launch(void* const* d_in, const int* in_sizes, int n_in,
                              void* d_out, int out_size, void* d_ws, size_t ws_size,
                              hipStream_t stream) {
  const float* x      = (const float*)d_in[0];
  const float* h0     = (const float*)d_in[1];
  const float* c0     = (const float*)d_in[2];
  const float* hhat0  = (const float*)d_in[3];
  const float* chat0  = (const float*)d_in[4];
  const float* hweight= (const float*)d_in[5];
  const float* hbias  = (const float*)d_in[6];
  const float* zw_h   = (const float*)d_in[7];
  const float* zw_x   = (const float*)d_in[8];
  const float* zw_b   = (const float*)d_in[9];
  const float* zb_h   = (const float*)d_in[10];
  const float* zb_x   = (const float*)d_in[11];
  const float* dw_h   = (const float*)d_in[12];
  const float* dw_x   = (const float*)d_in[13];
  const float* dw_b   = (const float*)d_in[14];
  const float* weight = (const float*)d_in[15];
  const float* bias   = (const float*)d_in[16];
  float* out = (float*)d_out;

  char* w = (char*)d_ws;
  auto take = [&](size_t bytes) { char* p = w; w += (bytes + 255) & ~(size_t)255; return p; };
  u16*   hcatb  = (u16*)take(2048ull * 2304 * 2);
  u16*   btc    = (u16*)take(5120ull * 2304 * 2);
  u16*   zwT    = (u16*)take(768ull * 256 * 2);
  u16*   dwT    = (u16*)take(12ull * 1024 * 64 * 2);
  u16*   grawb  = (u16*)take(2048ull * 4096 * 2);
  float* hgbuf  = (float*)take(2048ull * 1024 * 4);
  u16*   hhat1b = (u16*)take(2048ull * 256 * 2);
  u16*   zb16   = (u16*)take(2048ull * 768 * 2);

  float* h1_o    = out;
  float* c1_o    = out + 2048 * 1024;
  float* hhat1_o = out + 2 * 2048 * 1024;
  float* chat1_o = out + 2 * 2048 * 1024 + 2048 * 256;

  k_prep<<<4608 + 5760 + 480, 256, 0, stream>>>(
      hhat0, h0, x, weight, hweight, zw_h, zw_x, zw_b, dw_h, dw_x, dw_b,
      hcatb, btc, zwT, dwT);

  k_gemm_main<<<dim3(40, 16), 512, 0, stream>>>(hcatb, btc, hgbuf, grawb);

  k_hyper_act<<<2048, 256, 0, stream>>>(hgbuf, hbias, chat0, chat1_o, hhat1_o, hhat1b);

  k_gemm_z<<<dim3(6, 32), 256, 0, stream>>>(hhat1b, zwT, zb_h, zb_x, zb16);

  k_dmod_lstm<<<dim3(16, 32), 256, 0, stream>>>(zb16, dwT, grawb, bias, c0, h1_o, c1_o);
}